// Round 5
// baseline (289.376 us; speedup 1.0000x reference)
//
#include <hip/hip_runtime.h>

typedef __attribute__((ext_vector_type(8))) short bf16x8;
typedef __attribute__((ext_vector_type(4))) float f32x4;

#define D_DIM 256
#define NROW  8192

__device__ __forceinline__ unsigned short f2bf(float x) {
  unsigned int u = __float_as_uint(x);
  u += 0x7fffu + ((u >> 16) & 1u);   // round-to-nearest-even
  return (unsigned short)(u >> 16);
}

__device__ __forceinline__ void gload_lds16(const void* g, void* l) {
  __builtin_amdgcn_global_load_lds((__attribute__((address_space(1))) void*)g,
                                   (__attribute__((address_space(3))) void*)l,
                                   16, 0, 0);
}

// One wave per row (D=256 -> 4 floats/lane). fp32 softmax, bf16 output.
__global__ __launch_bounds__(256) void softmax_rows(const float* __restrict__ S,
                                                    unsigned short* __restrict__ P) {
  const int row  = blockIdx.x * 4 + (threadIdx.x >> 6);
  const int lane = threadIdx.x & 63;
  float4 v = ((const float4*)(S + row * D_DIM))[lane];
  float m = fmaxf(fmaxf(v.x, v.y), fmaxf(v.z, v.w));
#pragma unroll
  for (int off = 32; off > 0; off >>= 1) m = fmaxf(m, __shfl_xor(m, off));
  float e0 = __expf(v.x - m), e1 = __expf(v.y - m);
  float e2 = __expf(v.z - m), e3 = __expf(v.w - m);
  float s = e0 + e1 + e2 + e3;
#pragma unroll
  for (int off = 32; off > 0; off >>= 1) s += __shfl_xor(s, off);
  const float inv = 1.0f / s;
  ushort4 o;
  o.x = f2bf(e0 * inv); o.y = f2bf(e1 * inv);
  o.z = f2bf(e2 * inv); o.w = f2bf(e3 * inv);
  ((ushort4*)(P + row * D_DIM))[lane] = o;
}

__global__ __launch_bounds__(256) void cast_v(const float* __restrict__ V,
                                              unsigned short* __restrict__ Vb) {
  const int i = blockIdx.x * 256 + threadIdx.x;  // one float4 per thread
  float4 v = ((const float4*)V)[i];
  ushort4 o;
  o.x = f2bf(v.x); o.y = f2bf(v.y); o.z = f2bf(v.z); o.w = f2bf(v.w);
  ((ushort4*)Vb)[i] = o;
}

// ---- GEMM -------------------------------------------------------------------
// O[i,j] = sum_k P[i,k] * Vb[j,k].  128x128 tile, BK=32, double-buffered
// 32 KB LDS -> 4 blocks/CU for store/drain overlap. Swizzle: 16B-chunk
// c ^= (row>>1)&3 within each 64 B row -> 2-way banks (free) on ds_read_b128.
// Applied source-side (gload_lds dest must stay linear) and read-side.
__global__ __launch_bounds__(256, 4) void gemm_bt(const unsigned short* __restrict__ P,
                                                  const unsigned short* __restrict__ Vb,
                                                  float* __restrict__ O) {
  // 32 KB: buf0 { A[0,4096) B[4096,8192) } shorts, buf1 at +8192 shorts.
  // Epilogue reuses the first 17408 B as per-wave fp32 transpose buffers.
  __shared__ unsigned short smem[16384];

  const int t    = threadIdx.x;
  const int lane = t & 63;
  const int wave = t >> 6;
  const int wm   = (wave & 1) * 64;
  const int wn   = (wave >> 1) * 64;

  // XCD stripe mapping: xcd = id%8 owns bm in [xcd*8, xcd*8+8), bm-fastest.
  const int id  = blockIdx.x;
  const int xcd = id & 7;
  const int q   = id >> 3;
  const int bm  = xcd * 8 + (q & 7);
  const int bn  = q >> 3;

  f32x4 acc[4][4] = {};

  // Staging: thread t covers A rows {srow, srow+64} and B rows {srow, srow+64},
  // 16B chunk (t&3) of the 64 B row. Global column carries the inverse swizzle
  // so the linear LDS write leaves data at chunk (c ^ (row>>1)&3).
  // Note (srow+64)>>1 & 3 == srow>>1 & 3, so one xg serves both row passes.
  const int srow = t >> 2;
  const int xg   = (((t & 3) ^ ((srow >> 1) & 3)) * 8);   // swizzled col (shorts)
  const unsigned short* ga = P  + (size_t)(bm * 128 + srow) * D_DIM + xg;
  const unsigned short* gb = Vb + (size_t)(bn * 128 + srow) * D_DIM + xg;
  unsigned short* l0 = smem + t * 8;                       // byte offset t*16

  // Fragment addressing: A[m=lane&15][k-chunk = lane>>4]
  const int arow = wm + (lane & 15);
  const int brow = wn + (lane & 15);
  const int kch  = lane >> 4;

  // ---- 2-phase double-buffered K loop (8 tiles of BK=32) ----
  // prologue: stage tile 0 into buf0
  {
    gload_lds16(ga, l0);
    gload_lds16(ga + 64 * D_DIM, l0 + 2048);
    gload_lds16(gb, l0 + 4096);
    gload_lds16(gb + 64 * D_DIM, l0 + 6144);
    asm volatile("s_waitcnt vmcnt(0)" ::: "memory");
    __builtin_amdgcn_s_barrier();
    __builtin_amdgcn_sched_barrier(0);
  }

#pragma unroll
  for (int tk = 0; tk < 8; ++tk) {
    const unsigned short* cur = smem + (tk & 1) * 8192;
    unsigned short*       nxt = l0 + ((tk & 1) ^ 1) * 8192;
    if (tk < 7) {                                  // prefetch tile tk+1
      const int ko = (tk + 1) * 32;
      gload_lds16(ga + ko,               nxt);
      gload_lds16(ga + 64 * D_DIM + ko,  nxt + 2048);
      gload_lds16(gb + ko,               nxt + 4096);
      gload_lds16(gb + 64 * D_DIM + ko,  nxt + 6144);
    }
    // compute tile tk from cur (A at cur, B at cur+4096)
    bf16x8 af[4], bfr[4];
#pragma unroll
    for (int mi = 0; mi < 4; ++mi) {
      const int r = arow + mi * 16;
      af[mi] = *(const bf16x8*)&cur[r * 32 + ((kch ^ ((r >> 1) & 3)) * 8)];
    }
#pragma unroll
    for (int ni = 0; ni < 4; ++ni) {
      const int r = brow + ni * 16;
      bfr[ni] = *(const bf16x8*)&cur[4096 + r * 32 + ((kch ^ ((r >> 1) & 3)) * 8)];
    }
#pragma unroll
    for (int mi = 0; mi < 4; ++mi)
#pragma unroll
      for (int ni = 0; ni < 4; ++ni)
        acc[mi][ni] = __builtin_amdgcn_mfma_f32_16x16x32_bf16(af[mi], bfr[ni],
                                                              acc[mi][ni], 0, 0, 0);
    if (tk < 7) {
      asm volatile("s_waitcnt vmcnt(0)" ::: "memory");
      __builtin_amdgcn_s_barrier();
      __builtin_amdgcn_sched_barrier(0);
    }
  }

  __syncthreads();   // all waves done reading K-loop LDS; epilogue reuses it

  // ---- Epilogue: per-wave LDS transpose in 16-row passes, NT float4 stores --
  // MFMA C/D layout: col = lane&15, row = (lane>>4)*4 + reg.
  // Per-wave buffer: 16 rows x 68 floats (pad +4 breaks bank aliasing).
  float* smf = (float*)smem;
  float* ep  = smf + wave * 1088;
  const int qrow = (lane >> 4) * 4;          // 0,4,8,12
  const int qcol = lane & 15;
  const size_t orow0 = (size_t)(bm * 128 + wm);
  const int    ocol0 = bn * 128 + wn + (lane & 15) * 4;

#pragma unroll
  for (int mi = 0; mi < 4; ++mi) {           // four 16-row passes
#pragma unroll
    for (int ni = 0; ni < 4; ++ni)
#pragma unroll
      for (int r = 0; r < 4; ++r)
        ep[(qrow + r) * 68 + ni * 16 + qcol] = acc[mi][ni][r];
    // wave-local: ds_write -> ds_read same region is wave-ordered (lgkmcnt)
#pragma unroll
    for (int qq = 0; qq < 4; ++qq) {
      const int rl = qq * 4 + (lane >> 4);   // 0..15 within pass
      f32x4 vv = *(const f32x4*)&ep[rl * 68 + (lane & 15) * 4];
      __builtin_nontemporal_store(vv,
          (f32x4*)&O[(orow0 + mi * 16 + rl) * NROW + ocol0]);
    }
  }
}

extern "C" void kernel_launch(void* const* d_in, const int* in_sizes, int n_in,
                              void* d_out, int out_size, void* d_ws, size_t ws_size,
                              hipStream_t stream) {
  const float* S = (const float*)d_in[0];   // [8192, 256] fp32
  const float* V = (const float*)d_in[1];   // [8192, 256] fp32
  float* O = (float*)d_out;                 // [8192, 8192] fp32

  unsigned short* P  = (unsigned short*)d_ws;          // 4 MB bf16 softmax(S)
  unsigned short* Vb = P + (size_t)NROW * D_DIM;       // 4 MB bf16 V

  softmax_rows<<<NROW / 4, 256, 0, stream>>>(S, P);
  cast_v<<<(NROW * D_DIM / 4) / 256, 256, 0, stream>>>(V, Vb);
  gemm_bt<<<NROW / 128 * (NROW / 128), 256, 0, stream>>>(P, Vb, O);
}